// Round 13
// baseline (64.988 us; speedup 1.0000x reference)
//
#include <hip/hip_runtime.h>
#include <math.h>

#define H       2048
#define E       64
#define TOKENS  16384
#define BATCH   4
#define NBLK    512

typedef _Float16 f16x8  __attribute__((ext_vector_type(8)));
typedef float    f32x16 __attribute__((ext_vector_type(16)));

// ws float offsets
#define WHI_OFF  0          // 131072 f16 = 65536 floats
#define WLO_OFF  65536      // 131072 f16
#define PART_OFF 131072     // NBLK * 128 floats (psum[64] | cnt[64])

// ---- W fp32 -> tiled f16 hi/lo in 32x32x16 B-fragment order (proven r5) ----
// slot s = (kg*2 + et)*64 + l ; e = et*32 + (l&31) ; k = kg*16 + (l>>5)*8 + j
__global__ __launch_bounds__(256)
void wconv(const float* __restrict__ W, _Float16* __restrict__ whi,
           _Float16* __restrict__ wlo)
{
    const int s  = blockIdx.x * 256 + threadIdx.x;   // 0..16383
    const int kg = s >> 7;
    const int et = (s >> 6) & 1;
    const int l  = s & 63;
    const int e  = et * 32 + (l & 31);
    const int kb = kg * 16 + ((l >> 5) << 3);
    const float4 a = *(const float4*)(W + (size_t)e * H + kb);
    const float4 b = *(const float4*)(W + (size_t)e * H + kb + 4);
    const float xv[8] = {a.x, a.y, a.z, a.w, b.x, b.y, b.z, b.w};
    f16x8 hi, lo;
    #pragma unroll
    for (int j = 0; j < 8; ++j) {
        const _Float16 h = (_Float16)xv[j];
        hi[j] = h;
        lo[j] = (_Float16)(xv[j] - (float)h);
    }
    *(f16x8*)(whi + (size_t)s * 8) = hi;
    *(f16x8*)(wlo + (size_t)s * 8) = lo;
}

// ---- main: 512 blocks x 1024 thr (2 blocks/CU = 2048 thr = 32 waves/CU) ----
// wave = (ks 0..7, et 0..1): 32 tokens x 32 experts x K=256, one f32x16 acc.
// Lean VGPR (<=64) so all 8 waves/SIMD are resident -> 2x memory concurrency.
__global__ __launch_bounds__(1024, 8)
void router_main(const float* __restrict__ x,
                 const _Float16* __restrict__ whi,
                 const _Float16* __restrict__ wlo,
                 float* __restrict__ out,
                 float* __restrict__ part)
{
    __shared__ float lds[16384];   // 64 KB: [8 ks][32 t][64 e] partials, then reused

    const int tid = threadIdx.x;
    const int l   = tid & 63;
    const int w   = tid >> 6;      // 0..15
    const int et  = w & 1;
    const int ks  = w >> 1;        // 0..7
    const int la  = l & 31;
    const int hi5 = l >> 5;

    const int    trow = blockIdx.x * 32 + la;                // A row = lane&31
    const float* xb   = x + (size_t)trow * H + ks * 256 + (hi5 << 3);
    const f16x8* bhp  = (const f16x8*)whi + (size_t)(ks * 16) * 128 + et * 64 + l;
    const f16x8* blp  = (const f16x8*)wlo + (size_t)(ks * 16) * 128 + et * 64 + l;

    f32x16 acc;
    #pragma unroll
    for (int i = 0; i < 16; ++i) acc[i] = 0.f;

    // 1-deep prefetch (TLP via 8 waves/SIMD covers the rest)
    float4 a0c = *(const float4*)xb, a1c = *(const float4*)(xb + 4);
    f16x8  bhc = bhp[0],             blc = blp[0];

    #pragma unroll
    for (int kk = 0; kk < 16; ++kk) {
        float4 a0n = a0c, a1n = a1c;
        f16x8  bhn = bhc, bln = blc;
        if (kk < 15) {
            a0n = *(const float4*)(xb + (kk + 1) * 16);
            a1n = *(const float4*)(xb + (kk + 1) * 16 + 4);
            bhn = bhp[(kk + 1) * 128];
            bln = blp[(kk + 1) * 128];
        }
        const float xv[8] = {a0c.x, a0c.y, a0c.z, a0c.w, a1c.x, a1c.y, a1c.z, a1c.w};
        f16x8 ahi, alo;
        #pragma unroll
        for (int j = 0; j < 8; ++j) {
            const _Float16 h = (_Float16)xv[j];
            ahi[j] = h;
            alo[j] = (_Float16)(xv[j] - (float)h);
        }
        acc = __builtin_amdgcn_mfma_f32_32x32x16_f16(ahi, bhc, acc, 0, 0, 0);
        acc = __builtin_amdgcn_mfma_f32_32x32x16_f16(ahi, blc, acc, 0, 0, 0);
        acc = __builtin_amdgcn_mfma_f32_32x32x16_f16(alo, bhc, acc, 0, 0, 0);
        a0c = a0n; a1c = a1n; bhc = bhn; blc = bln;
    }

    // ---- write partials: row=(r&3)+8*(r>>2)+4*hi5, col=et*32+la (disjoint per wave)
    #pragma unroll
    for (int r = 0; r < 16; ++r) {
        const int row = (r & 3) + 8 * (r >> 2) + 4 * hi5;
        lds[(ks * 32 + row) * 64 + et * 32 + la] = acc[r];
    }
    __syncthreads();

    // ---- reduce over 8 ks (threads 0..511: t=tid>>4, c4=(tid&15)*4), write [32][65]
    if (tid < 512) {
        const int t = tid >> 4, c4 = (tid & 15) * 4;
        float s0 = 0.f, s1 = 0.f, s2 = 0.f, s3 = 0.f;
        #pragma unroll
        for (int k2 = 0; k2 < 8; ++k2) {
            const float4 v = *(const float4*)&lds[(k2 * 32 + t) * 64 + c4];
            s0 += v.x; s1 += v.y; s2 += v.z; s3 += v.w;
        }
        __syncthreads();    // all partial reads done before overwrite
        lds[t * 65 + c4 + 0] = s0;
        lds[t * 65 + c4 + 1] = s1;
        lds[t * 65 + c4 + 2] = s2;
        lds[t * 65 + c4 + 3] = s3;
    } else {
        __syncthreads();
    }
    __syncthreads();

    // ---- wave-0 epilogue: lanes 0..31 = tokens (proven serial structure)
    #define SC_OFF   2112
    #define HIST_OFF 6272
    int i1 = 0, i2 = 0;
    if (w == 0 && l < 32) {
        float lg[64];
        #pragma unroll
        for (int e = 0; e < 64; ++e) lg[e] = lds[l * 65 + e];
        float v1 = lg[0];
        #pragma unroll
        for (int e = 1; e < 64; ++e) { if (lg[e] > v1) { v1 = lg[e]; i1 = e; } }
        float v2 = -INFINITY;
        #pragma unroll
        for (int e = 0; e < 64; ++e) { if (e != i1 && lg[e] > v2) { v2 = lg[e]; i2 = e; } }
        float den = 0.f;
        #pragma unroll
        for (int e = 0; e < 64; ++e) den += __expf(lg[e] - v1);
        const float inv_den = 1.f / den;
        const float s1 = inv_den;                    // exp(v1-v1)/den
        const float s2 = __expf(v2 - v1) * inv_den;
        const float rs = 1.f / (s1 + s2 + 1e-20f);
        const int gt = blockIdx.x * 32 + l;
        *(float2*)&out[2 * gt]              = make_float2((float)i1, (float)i2);
        *(float2*)&out[2 * TOKENS + 2 * gt] = make_float2(s1 * rs, s2 * rs);
        // scores, rotated columns for conflict-free column sums
        #pragma unroll
        for (int e = 0; e < 64; ++e)
            lds[SC_OFF + l * 64 + ((e + l) & 63)] = __expf(lg[e] - v1) * inv_den;
    }
    __syncthreads();
    if (w == 0) {
        float cs = 0.f;                  // expert l's score sum over 32 tokens
        #pragma unroll
        for (int r = 0; r < 32; ++r) cs += lds[SC_OFF + r * 64 + ((l + r) & 63)];
        part[blockIdx.x * 128 + l] = cs;
        lds[HIST_OFF + l] = 0.f;
    }
    __syncthreads();
    if (w == 0 && l < 32) {
        atomicAdd(&lds[HIST_OFF + i1], 1.f);
        atomicAdd(&lds[HIST_OFF + i2], 1.f);
    }
    __syncthreads();
    if (w == 0) part[blockIdx.x * 128 + 64 + l] = lds[HIST_OFF + l];
}

// ---- aux loss finalize: reduce 512 per-block partials (proven r5) ----
__global__ __launch_bounds__(256)
void router_aux(const float* __restrict__ part, float* __restrict__ out)
{
    const int tid = threadIdx.x;    // 256 = BATCH*E
    const int b = tid >> 6, e = tid & 63;
    float ps = 0.f, ct = 0.f;
    for (int j = 0; j < 128; ++j) {          // 128 blocks per batch
        const int base = (b * 128 + j) * 128;
        ps += part[base + e];                // coalesced: lanes -> consecutive e
        ct += part[base + 64 + e];
    }
    // ce = ct * E/(S*k); meanprob = ps/S
    float val = ct * (64.0f / (4096.0f * 2.0f)) * (ps / 4096.0f);
    #pragma unroll
    for (int off = 32; off > 0; off >>= 1) val += __shfl_xor(val, off, 64);
    __shared__ float red[4];
    if ((tid & 63) == 0) red[tid >> 6] = val;
    __syncthreads();
    if (tid == 0)
        out[4 * TOKENS] = (red[0] + red[1] + red[2] + red[3]) * (0.001f / 4.0f);
}

extern "C" void kernel_launch(void* const* d_in, const int* in_sizes, int n_in,
                              void* d_out, int out_size, void* d_ws, size_t ws_size,
                              hipStream_t stream)
{
    (void)in_sizes; (void)n_in; (void)out_size; (void)ws_size;
    const float* x = (const float*)d_in[0];
    const float* W = (const float*)d_in[1];
    float* out = (float*)d_out;
    float* ws  = (float*)d_ws;

    _Float16* whi  = (_Float16*)(ws + WHI_OFF);
    _Float16* wlo  = (_Float16*)(ws + WLO_OFF);
    float*    part = ws + PART_OFF;

    hipLaunchKernelGGL(wconv, dim3(64), dim3(256), 0, stream, W, whi, wlo);
    hipLaunchKernelGGL(router_main, dim3(NBLK), dim3(1024), 0, stream,
                       x, whi, wlo, out, part);
    hipLaunchKernelGGL(router_aux, dim3(1), dim3(256), 0, stream, part, out);
}